// Round 3
// baseline (642.656 us; speedup 1.0000x reference)
//
#include <hip/hip_runtime.h>
#include <math.h>

// ---------------------------------------------------------------------------
// ADCGNN amazon: N=50000, E=1.6M, IN=128, H=64, C=2, K=3
//
// Layout convention:
//   SoA  arrT[feat][node] (stride N)  -> coalesced per-thread k-loops
//   AoS  arr[node][feat]  (row 256 B) -> spmm gather inputs only
//
// Pipeline:
//   build: bucket_count -> bucket_scan -> bucket_scatter -> csr_build
//   dense1:    h1T = relu(X@W1+b1)           (4 thr/node, LDS-staged X, SoA out)
//   dense2res: h(SoA)+hs(AoS via LDS)+res(SoA) from h1T
//   spmm1: u1T(SoA via LDS) + u1s(AoS) = S h ;  spmm2: u2T(SoA) = S^2 h
//   attnfuse: 4 thr/node, all-SoA, full tail -> logits
// ---------------------------------------------------------------------------

#define BSHIFT 7
#define BNODES 128
#define BMAX   512
#define EPT    32
#define CHUNK  (256 * EPT)
#define CAP    8192

__device__ __forceinline__ void fma4(float4& acc, float s, const float4 w) {
    acc.x += s * w.x; acc.y += s * w.y; acc.z += s * w.z; acc.w += s * w.w;
}

// ----------------------------- graph build ---------------------------------

__global__ __launch_bounds__(256) void bucket_count_k(const int* __restrict__ dst,
                                                      int* __restrict__ bucketCount,
                                                      int E, int B) {
    __shared__ int cnt[BMAX];
    for (int i = threadIdx.x; i < B; i += 256) cnt[i] = 0;
    __syncthreads();
    int base = blockIdx.x * CHUNK;
    #pragma unroll
    for (int t = 0; t < EPT; t++) {
        int e = base + t * 256 + threadIdx.x;
        if (e < E) atomicAdd(&cnt[dst[e] >> BSHIFT], 1);
    }
    __syncthreads();
    for (int i = threadIdx.x; i < B; i += 256)
        if (cnt[i] > 0) atomicAdd(&bucketCount[i], cnt[i]);
}

__global__ __launch_bounds__(64) void bucket_scan_k(const int* __restrict__ bucketCount,
                                                    int* __restrict__ bucketPtr,
                                                    int* __restrict__ bucketCursor,
                                                    int* __restrict__ rowPtr,
                                                    int B, int N, int E) {
    int lane = threadIdx.x;
    const int PT = (BMAX + 63) / 64;
    int v[PT]; int s = 0;
    #pragma unroll
    for (int t = 0; t < PT; t++) {
        int i = lane * PT + t;
        v[t] = (i < B) ? bucketCount[i] : 0;
        s += v[t];
    }
    int x = s;
    #pragma unroll
    for (int off = 1; off < 64; off <<= 1) {
        int y = __shfl_up(x, off, 64);
        if (lane >= off) x += y;
    }
    int run = x - s;
    #pragma unroll
    for (int t = 0; t < PT; t++) {
        int i = lane * PT + t;
        if (i < B) { bucketPtr[i] = run; bucketCursor[i] = run; }
        run += v[t];
    }
    if (lane == 63) bucketPtr[B] = x;
    if (lane == 0) rowPtr[N] = E;
}

__global__ __launch_bounds__(256) void bucket_scatter_k(const int* __restrict__ src,
                                                        const int* __restrict__ dst,
                                                        int* __restrict__ bucketCursor,
                                                        int* __restrict__ ebuf,
                                                        int E, int B) {
    __shared__ int cnt[BMAX];
    __shared__ int base[BMAX];
    __shared__ int cur[BMAX];
    for (int i = threadIdx.x; i < B; i += 256) { cnt[i] = 0; cur[i] = 0; }
    __syncthreads();
    int cbase = blockIdx.x * CHUNK;
    int d[EPT];
    #pragma unroll
    for (int t = 0; t < EPT; t++) {
        int e = cbase + t * 256 + threadIdx.x;
        d[t] = (e < E) ? dst[e] : -1;
        if (d[t] >= 0) atomicAdd(&cnt[d[t] >> BSHIFT], 1);
    }
    __syncthreads();
    for (int i = threadIdx.x; i < B; i += 256)
        if (cnt[i] > 0) base[i] = atomicAdd(&bucketCursor[i], cnt[i]);
    __syncthreads();
    #pragma unroll
    for (int t = 0; t < EPT; t++) {
        int e = cbase + t * 256 + threadIdx.x;
        if (d[t] >= 0) {
            int b = d[t] >> BSHIFT;
            int c = atomicAdd(&cur[b], 1);
            int pack = (src[e] & 0xFFFF) | ((d[t] & (BNODES - 1)) << 16);
            ebuf[base[b] + c] = pack;
        }
    }
}

__global__ __launch_bounds__(256) void csr_build_k(const int* __restrict__ ebuf,
                                                   const int* __restrict__ bucketPtr,
                                                   int* __restrict__ rowPtr,
                                                   float* __restrict__ dinv,
                                                   int* __restrict__ srcSorted,
                                                   int N) {
    __shared__ int deg[BNODES];
    __shared__ int rp[BNODES + 1];
    __shared__ int cur[BNODES];
    __shared__ int stage[CAP];
    int b = blockIdx.x;
    int nodeBase = b << BSHIFT;
    int nNodes = min(BNODES, N - nodeBase);
    int eBase = bucketPtr[b];
    int eCnt = bucketPtr[b + 1] - eBase;
    for (int i = threadIdx.x; i < BNODES; i += 256) deg[i] = 0;
    __syncthreads();
    for (int i = threadIdx.x; i < eCnt; i += 256)
        atomicAdd(&deg[(ebuf[eBase + i] >> 16) & (BNODES - 1)], 1);
    __syncthreads();
    if (threadIdx.x < 64) {
        int lane = threadIdx.x;
        int d0 = deg[2 * lane], d1 = deg[2 * lane + 1];
        int s = d0 + d1;
        int x = s;
        #pragma unroll
        for (int off = 1; off < 64; off <<= 1) {
            int y = __shfl_up(x, off, 64);
            if (lane >= off) x += y;
        }
        int ex = x - s;
        rp[2 * lane] = ex;
        rp[2 * lane + 1] = ex + d0;
        cur[2 * lane] = ex;
        cur[2 * lane + 1] = ex + d0;
        if (lane == 63) rp[BNODES] = x;
    }
    __syncthreads();
    for (int j = threadIdx.x; j < nNodes; j += 256) {
        rowPtr[nodeBase + j] = eBase + rp[j];
        int dg = deg[j];
        dinv[nodeBase + j] = rsqrtf((float)(dg > 1 ? dg : 1));
    }
    if (eCnt <= CAP) {
        for (int i = threadIdx.x; i < eCnt; i += 256) {
            int p = ebuf[eBase + i];
            int ld = (p >> 16) & (BNODES - 1);
            int pos = atomicAdd(&cur[ld], 1);
            stage[pos] = p & 0xFFFF;
        }
        __syncthreads();
        for (int i = threadIdx.x; i < eCnt; i += 256)
            srcSorted[eBase + i] = stage[i];
    } else {
        for (int i = threadIdx.x; i < eCnt; i += 256) {
            int p = ebuf[eBase + i];
            int ld = (p >> 16) & (BNODES - 1);
            int pos = atomicAdd(&cur[ld], 1);
            srcSorted[eBase + pos] = p & 0xFFFF;
        }
    }
}

// ----------------------------- dense1 (4 thr/node) -------------------------
// Block: 256 threads = 64 nodes x 4 subs. X staged in LDS (coalesced), each
// sub computes a 16-wide output slice; weights from L1 (per-sub base).

#define D1_NODES 64
#define D1_PAD   132

__global__ __launch_bounds__(256) void dense1_k(const float* __restrict__ Xg,
                                                const float* __restrict__ W1,
                                                const float* __restrict__ b1,
                                                float* __restrict__ h1T, int N) {
    __shared__ float xs[D1_NODES * D1_PAD];
    int n0 = blockIdx.x * D1_NODES;
    const float4* X4 = (const float4*)Xg;
    #pragma unroll
    for (int r = 0; r < 8; r++) {
        int idx = r * 256 + threadIdx.x;      // 0..2047
        int row = idx >> 5, col = idx & 31;   // float4 units
        int gn = n0 + row;
        float4 v = (gn < N) ? X4[(size_t)gn * 32 + col] : make_float4(0.f, 0.f, 0.f, 0.f);
        *(float4*)&xs[row * D1_PAD + col * 4] = v;
    }
    __syncthreads();
    int nl = threadIdx.x >> 2;
    int sub = threadIdx.x & 3;
    int n = n0 + nl;
    if (n >= N) return;
    const float4* Wp = (const float4*)W1 + sub * 4;   // slice base, row stride 16
    const float4* Bp = (const float4*)b1 + sub * 4;
    float4 acc[4] = {Bp[0], Bp[1], Bp[2], Bp[3]};
    const float* xr = &xs[nl * D1_PAD];
    #pragma unroll 4
    for (int k = 0; k < 128; k++) {
        float a = xr[k];
        const float4* wr = Wp + k * 16;
        fma4(acc[0], a, wr[0]); fma4(acc[1], a, wr[1]);
        fma4(acc[2], a, wr[2]); fma4(acc[3], a, wr[3]);
    }
    #pragma unroll
    for (int i = 0; i < 4; i++) {
        int j = sub * 16 + i * 4;
        h1T[(size_t)(j + 0) * N + n] = fmaxf(acc[i].x, 0.f);
        h1T[(size_t)(j + 1) * N + n] = fmaxf(acc[i].y, 0.f);
        h1T[(size_t)(j + 2) * N + n] = fmaxf(acc[i].z, 0.f);
        h1T[(size_t)(j + 3) * N + n] = fmaxf(acc[i].w, 0.f);
    }
}

// ----------------------------- dense2res -----------------------------------
// Node per thread; h1T SoA streamed (coalesced); weights scalar-promoted.
// Outputs: hT (SoA direct), resT (SoA direct), hs (AoS via LDS bounce).

#define D2_PAD 68

__global__ __launch_bounds__(256) void dense2res_k(const float* __restrict__ h1T,
                                                   const float* __restrict__ W2,
                                                   const float* __restrict__ b2,
                                                   const float* __restrict__ Wres,
                                                   const float* __restrict__ bres,
                                                   const float* __restrict__ dinv,
                                                   float* __restrict__ hT,
                                                   float* __restrict__ hsAoS,
                                                   float* __restrict__ resT, int N) {
    __shared__ float lds[256 * D2_PAD];
    int n0 = blockIdx.x * 256;
    int n = n0 + threadIdx.x;
    bool act = (n < N);
    const float4* W = (const float4*)W2;
    const float4* B = (const float4*)b2;
    float4 acc[16];
    #pragma unroll
    for (int j = 0; j < 16; j++) acc[j] = B[j];
    if (act) {
        #pragma unroll 1
        for (int kc = 0; kc < 16; kc++) {
            float4 a;
            a.x = h1T[(size_t)(4 * kc + 0) * N + n];
            a.y = h1T[(size_t)(4 * kc + 1) * N + n];
            a.z = h1T[(size_t)(4 * kc + 2) * N + n];
            a.w = h1T[(size_t)(4 * kc + 3) * N + n];
            const float4* wrow = W + kc * 64;
            #pragma unroll
            for (int j = 0; j < 16; j++) {
                fma4(acc[j], a.x, wrow[j]);
                fma4(acc[j], a.y, wrow[16 + j]);
                fma4(acc[j], a.z, wrow[32 + j]);
                fma4(acc[j], a.w, wrow[48 + j]);
            }
        }
    }
    float di = act ? dinv[n] : 0.f;
    float* myrow = &lds[threadIdx.x * D2_PAD];
    #pragma unroll
    for (int j = 0; j < 16; j++) {
        float4 v = acc[j];
        v.x = fmaxf(v.x, 0.f); v.y = fmaxf(v.y, 0.f);
        v.z = fmaxf(v.z, 0.f); v.w = fmaxf(v.w, 0.f);
        acc[j] = v;
        if (act) {
            hT[(size_t)(4 * j + 0) * N + n] = v.x;
            hT[(size_t)(4 * j + 1) * N + n] = v.y;
            hT[(size_t)(4 * j + 2) * N + n] = v.z;
            hT[(size_t)(4 * j + 3) * N + n] = v.w;
        }
        myrow[4 * j + 0] = v.x * di;
        myrow[4 * j + 1] = v.y * di;
        myrow[4 * j + 2] = v.z * di;
        myrow[4 * j + 3] = v.w * di;
    }
    // res = h @ Wres + bres (h in registers)
    const float4* WR = (const float4*)Wres;
    const float4* BR = (const float4*)bres;
    float4 acc2[16];
    #pragma unroll
    for (int j = 0; j < 16; j++) acc2[j] = BR[j];
    #pragma unroll 1
    for (int kc = 0; kc < 16; kc++) {
        float4 a2 = acc[kc];
        const float4* wrow = WR + kc * 64;
        #pragma unroll
        for (int j = 0; j < 16; j++) {
            fma4(acc2[j], a2.x, wrow[j]);
            fma4(acc2[j], a2.y, wrow[16 + j]);
            fma4(acc2[j], a2.z, wrow[32 + j]);
            fma4(acc2[j], a2.w, wrow[48 + j]);
        }
    }
    if (act) {
        #pragma unroll
        for (int j = 0; j < 16; j++) {
            resT[(size_t)(4 * j + 0) * N + n] = acc2[j].x;
            resT[(size_t)(4 * j + 1) * N + n] = acc2[j].y;
            resT[(size_t)(4 * j + 2) * N + n] = acc2[j].z;
            resT[(size_t)(4 * j + 3) * N + n] = acc2[j].w;
        }
    }
    __syncthreads();
    // cooperative AoS write of hs: 256 rows x 16 float4
    float4* hs4 = (float4*)hsAoS;
    #pragma unroll
    for (int r = 0; r < 16; r++) {
        int idx = r * 256 + threadIdx.x;
        int row = idx >> 4, col = idx & 15;
        int gn = n0 + row;
        if (gn < N) hs4[(size_t)gn * 16 + col] = *(float4*)&lds[row * D2_PAD + col * 4];
    }
}

// ----------------------------- SPMM gather ---------------------------------
// Block = 1024 threads = 16 waves = 16 nodes. Edge loop unrolled x2.
// Output: SoA via block LDS transpose (+ optional AoS for next spmm).

#define SP_NODES 16
#define SP_PAD   68

__global__ __launch_bounds__(1024) void spmm_k(const float4* __restrict__ xs,
                                               const int* __restrict__ srcs,
                                               const int* __restrict__ rowPtr,
                                               const float* __restrict__ dinv,
                                               float* __restrict__ uT,
                                               float4* __restrict__ usAoS, int N) {
    __shared__ float rows[SP_NODES * SP_PAD];
    int w = threadIdx.x >> 6;
    int node0 = blockIdx.x * SP_NODES;
    int node = node0 + w;
    int lane = threadIdx.x & 63;
    int sub = lane >> 4, q = lane & 15;
    bool active = (node < N);
    if (active) {
        int s0 = rowPtr[node], s1 = rowPtr[node + 1];
        float4 a0 = make_float4(0.f, 0.f, 0.f, 0.f);
        float4 a1 = make_float4(0.f, 0.f, 0.f, 0.f);
        int i = s0 + sub;
        for (; i + 4 < s1; i += 8) {
            int sA = srcs[i];
            int sB = srcs[i + 4];
            float4 vA = xs[(size_t)sA * 16 + q];
            float4 vB = xs[(size_t)sB * 16 + q];
            a0.x += vA.x; a0.y += vA.y; a0.z += vA.z; a0.w += vA.w;
            a1.x += vB.x; a1.y += vB.y; a1.z += vB.z; a1.w += vB.w;
        }
        if (i < s1) {
            int sA = srcs[i];
            float4 vA = xs[(size_t)sA * 16 + q];
            a0.x += vA.x; a0.y += vA.y; a0.z += vA.z; a0.w += vA.w;
        }
        a0.x += a1.x; a0.y += a1.y; a0.z += a1.z; a0.w += a1.w;
        #pragma unroll
        for (int m = 16; m < 64; m <<= 1) {
            a0.x += __shfl_xor(a0.x, m, 64);
            a0.y += __shfl_xor(a0.y, m, 64);
            a0.z += __shfl_xor(a0.z, m, 64);
            a0.w += __shfl_xor(a0.w, m, 64);
        }
        if (sub == 0) {
            float di = dinv[node];
            float4 r = make_float4(a0.x * di, a0.y * di, a0.z * di, a0.w * di);
            if (usAoS) {
                float4 r2 = make_float4(r.x * di, r.y * di, r.z * di, r.w * di);
                usAoS[(size_t)node * 16 + q] = r2;
            }
            *(float4*)&rows[w * SP_PAD + q * 4] = r;
        }
    }
    __syncthreads();
    int j = threadIdx.x >> 4;     // feature 0..63
    int nn = threadIdx.x & 15;    // local node
    int gn = node0 + nn;
    if (gn < N) uT[(size_t)j * N + gn] = rows[nn * SP_PAD + j];
}

// ----------------------------- attn + fusion tail (4 thr/node) -------------
// All inputs SoA. mean_fused == h; attn_fused = ca*h+cb*u1+cc*u2.
// Each sub owns a 16-wide output slice of both GEMVs; quad shfl reductions.

__global__ __launch_bounds__(256) void attnfuse_k(const float* __restrict__ hT,
                                                  const float* __restrict__ u1T,
                                                  const float* __restrict__ u2T,
                                                  const float* __restrict__ resT,
                                                  const float* __restrict__ Wattn,
                                                  const float* __restrict__ battn,
                                                  const float* __restrict__ Wf1,
                                                  const float* __restrict__ bf1,
                                                  const float* __restrict__ Wf2,
                                                  const float* __restrict__ bf2,
                                                  const float* __restrict__ W3,
                                                  const float* __restrict__ b3,
                                                  const float* __restrict__ W4,
                                                  const float* __restrict__ b4,
                                                  float2* __restrict__ out, int N) {
    int t = blockIdx.x * 256 + threadIdx.x;
    int n = t >> 2;
    int sub = t & 3;
    if (n >= N) return;
    // --- attention scores (k-slice per sub, quad-reduced) ---
    const float4* WaV = (const float4*)Wattn + sub * 4;
    float th = 0.f, ta = 0.f, tb = 0.f;
    #pragma unroll
    for (int i = 0; i < 4; i++) {
        float4 wv = WaV[i];
        int kb = sub * 16 + i * 4;
        #define DOT_C(c, off) { size_t o = (size_t)(kb + off) * N + n; \
            th += hT[o] * wv.c; ta += u1T[o] * wv.c; tb += u2T[o] * wv.c; }
        DOT_C(x, 0) DOT_C(y, 1) DOT_C(z, 2) DOT_C(w, 3)
        #undef DOT_C
    }
    th += __shfl_xor(th, 1, 64); th += __shfl_xor(th, 2, 64);
    ta += __shfl_xor(ta, 1, 64); ta += __shfl_xor(ta, 2, 64);
    tb += __shfl_xor(tb, 1, 64); tb += __shfl_xor(tb, 2, 64);
    float ba = battn[0];
    float s0 = 0.75f * th + 1.5f * ta + 0.75f * tb + ba;
    float s1 = 1.5f * th - 1.5f * tb + ba;
    float s2 = 0.75f * th - 1.5f * ta + 0.75f * tb + ba;
    float m = fmaxf(s0, fmaxf(s1, s2));
    float e0 = expf(s0 - m), e1 = expf(s1 - m), e2 = expf(s2 - m);
    float inv = 1.f / (e0 + e1 + e2);
    float w0 = e0 * inv, w1 = e1 * inv, w2 = e2 * inv;
    float ca = 0.75f * w0 + 1.5f * w1 + 0.75f * w2;
    float cb = 1.5f * (w0 - w2);
    float cc = 0.75f * w0 - 1.5f * w1 + 0.75f * w2;
    // --- t = relu([af | h] @ Wf1 + bf1), own 16-wide slice ---
    const float4* Wf14 = (const float4*)Wf1 + sub * 4;   // row stride 16
    const float4* Bf1 = (const float4*)bf1 + sub * 4;
    float4 tacc[4] = {Bf1[0], Bf1[1], Bf1[2], Bf1[3]};
    #pragma unroll 4
    for (int k = 0; k < 64; k++) {
        size_t o = (size_t)k * N + n;
        float hv = hT[o], av = u1T[o], bv = u2T[o];
        float af = ca * hv + cb * av + cc * bv;
        const float4* wa = Wf14 + k * 16;
        const float4* wh = Wf14 + (64 + k) * 16;
        fma4(tacc[0], af, wa[0]); fma4(tacc[1], af, wa[1]);
        fma4(tacc[2], af, wa[2]); fma4(tacc[3], af, wa[3]);
        fma4(tacc[0], hv, wh[0]); fma4(tacc[1], hv, wh[1]);
        fma4(tacc[2], hv, wh[2]); fma4(tacc[3], hv, wh[3]);
    }
    const float4* Wf24 = (const float4*)Wf2 + sub * 4;
    float fwacc = 0.f;
    #pragma unroll
    for (int i = 0; i < 4; i++) {
        float4 v = tacc[i];
        v.x = fmaxf(v.x, 0.f); v.y = fmaxf(v.y, 0.f);
        v.z = fmaxf(v.z, 0.f); v.w = fmaxf(v.w, 0.f);
        float4 w = Wf24[i];
        fwacc += v.x * w.x + v.y * w.y + v.z * w.z + v.w * w.w;
    }
    fwacc += __shfl_xor(fwacc, 1, 64);
    fwacc += __shfl_xor(fwacc, 2, 64);
    fwacc += bf2[0];
    float fw = 1.f / (1.f + expf(-fwacc));
    float c_af = 0.1f * fw, c_mf = 1.f - fw;
    // --- g = relu(fused @ W3 + b3), own slice ---
    const float4* W34 = (const float4*)W3 + sub * 4;
    const float4* B3 = (const float4*)b3 + sub * 4;
    float4 g[4] = {B3[0], B3[1], B3[2], B3[3]};
    #pragma unroll 4
    for (int k = 0; k < 64; k++) {
        size_t o = (size_t)k * N + n;
        float hv = hT[o], av = u1T[o], bv = u2T[o], rv = resT[o];
        float af = ca * hv + cb * av + cc * bv;
        float f = c_af * af + c_mf * hv + 0.8f * rv;
        const float4* wr = W34 + k * 16;
        fma4(g[0], f, wr[0]); fma4(g[1], f, wr[1]);
        fma4(g[2], f, wr[2]); fma4(g[3], f, wr[3]);
    }
    // --- logits partial over own slice ---
    const float2* W42 = (const float2*)W4;
    float l0 = 0.f, l1 = 0.f;
    #pragma unroll
    for (int i = 0; i < 4; i++) {
        float4 v = g[i];
        v.x = fmaxf(v.x, 0.f); v.y = fmaxf(v.y, 0.f);
        v.z = fmaxf(v.z, 0.f); v.w = fmaxf(v.w, 0.f);
        int j = sub * 16 + i * 4;
        float2 wa = W42[j + 0], wb = W42[j + 1], wc = W42[j + 2], wd = W42[j + 3];
        l0 += v.x * wa.x + v.y * wb.x + v.z * wc.x + v.w * wd.x;
        l1 += v.x * wa.y + v.y * wb.y + v.z * wc.y + v.w * wd.y;
    }
    l0 += __shfl_xor(l0, 1, 64); l0 += __shfl_xor(l0, 2, 64);
    l1 += __shfl_xor(l1, 1, 64); l1 += __shfl_xor(l1, 2, 64);
    if (sub == 0) out[n] = make_float2(l0 + b4[0], l1 + b4[1]);
}

// ----------------------------- launch --------------------------------------

extern "C" void kernel_launch(void* const* d_in, const int* in_sizes, int n_in,
                              void* d_out, int out_size, void* d_ws, size_t ws_size,
                              hipStream_t stream) {
    const float* in_feat = (const float*)d_in[0];
    const int*   src     = (const int*)d_in[1];
    const int*   dst     = (const int*)d_in[2];
    const float* W1   = (const float*)d_in[3];
    const float* b1   = (const float*)d_in[4];
    const float* W2   = (const float*)d_in[5];
    const float* b2   = (const float*)d_in[6];
    const float* Wres = (const float*)d_in[7];
    const float* bres = (const float*)d_in[8];
    const float* Wattn = (const float*)d_in[9];
    const float* battn = (const float*)d_in[10];
    const float* Wf1  = (const float*)d_in[11];
    const float* bf1  = (const float*)d_in[12];
    const float* Wf2  = (const float*)d_in[13];
    const float* bf2  = (const float*)d_in[14];
    const float* W3   = (const float*)d_in[15];
    const float* b3   = (const float*)d_in[16];
    const float* W4   = (const float*)d_in[17];
    const float* b4   = (const float*)d_in[18];

    const int N = in_sizes[0] / 128;
    const int E = in_sizes[1];
    const int B = (N + BNODES - 1) >> BSHIFT;

    char* p = (char*)d_ws;
    auto take = [&](size_t bytes) -> char* {
        char* r = p;
        p += (bytes + 255) & ~(size_t)255;
        return r;
    };
    int*   bucketCount  = (int*)take((size_t)(B + 1) * 4);
    int*   bucketPtr    = (int*)take((size_t)(B + 1) * 4);
    int*   bucketCursor = (int*)take((size_t)(B + 1) * 4);
    int*   rowPtr       = (int*)take((size_t)(N + 1) * 4);
    float* dinv         = (float*)take((size_t)N * 4);
    int*   srcSorted    = (int*)take((size_t)E * 4);
    float* h1T  = (float*)take((size_t)N * 256);
    float* hT   = (float*)take((size_t)N * 256);
    float* hs   = (float*)take((size_t)N * 256);   // AoS for spmm1
    float* resT = (float*)take((size_t)N * 256);
    float* u1T  = (float*)take((size_t)N * 256);
    float* u1s  = (float*)take((size_t)N * 256);   // AoS for spmm2
    int*   ebuf = (int*)h1T;   // dead before dense1 writes h1T (stream order)
    float* u2T  = h1T;         // h1T dead after dense2res reads it

    int eb = (E + CHUNK - 1) / CHUNK;
    int d1b = (N + D1_NODES - 1) / D1_NODES;
    int nb = (N + 255) / 256;
    int spb = (N + SP_NODES - 1) / SP_NODES;
    int afb = ((N * 4) + 255) / 256;

    hipMemsetAsync(bucketCount, 0, (size_t)B * 4, stream);
    bucket_count_k<<<eb, 256, 0, stream>>>(dst, bucketCount, E, B);
    bucket_scan_k<<<1, 64, 0, stream>>>(bucketCount, bucketPtr, bucketCursor,
                                        rowPtr, B, N, E);
    bucket_scatter_k<<<eb, 256, 0, stream>>>(src, dst, bucketCursor, ebuf, E, B);
    csr_build_k<<<B, 256, 0, stream>>>(ebuf, bucketPtr, rowPtr, dinv, srcSorted, N);

    dense1_k<<<d1b, 256, 0, stream>>>(in_feat, W1, b1, h1T, N);
    dense2res_k<<<nb, 256, 0, stream>>>(h1T, W2, b2, Wres, bres, dinv,
                                        hT, hs, resT, N);

    spmm_k<<<spb, 1024, 0, stream>>>((const float4*)hs, srcSorted, rowPtr, dinv,
                                     u1T, (float4*)u1s, N);
    spmm_k<<<spb, 1024, 0, stream>>>((const float4*)u1s, srcSorted, rowPtr, dinv,
                                     u2T, nullptr, N);

    attnfuse_k<<<afb, 256, 0, stream>>>(hT, u1T, u2T, resT,
                                        Wattn, battn, Wf1, bf1, Wf2, bf2,
                                        W3, b3, W4, b4, (float2*)d_out, N);
}

// Round 4
// 431.319 us; speedup vs baseline: 1.4900x; 1.4900x over previous
//
#include <hip/hip_runtime.h>
#include <math.h>

// ---------------------------------------------------------------------------
// ADCGNN amazon: N=50000, E=1.6M, IN=128, H=64, C=2, K=3
// All node features AoS (row = 64 floats = 256 B). Lesson from R3: SoA +
// 4thr/node breaks wave coverage (16 nodes/wave) -> latency-bound. AoS wins.
//
// Pipeline:
//   build: bucket_count -> bucket_scan -> bucket_scatter -> csr_build
//   dense1:    h1 = relu(X@W1+b1)                     (thread/node, AoS)
//   dense2res: h, hs=h*dinv, res=h@Wres+bres, th=h.Wattn  (LDS-bounced writes)
//   spmm1:     u1 = dinv*(A^T hs), u1s = u1*dinv, ta = u1.Wattn
//   tail:      wave/node: gather u2 (regs only) -> softmax -> Wf1/Wf2 ->
//              W3 -> W4 -> logits. u2 never hits HBM; wave-GEMV via shfl.
// ---------------------------------------------------------------------------

#define BSHIFT 7
#define BNODES 128
#define BMAX   512
#define EPT    32
#define CHUNK  (256 * EPT)
#define CAP    8192

__device__ __forceinline__ void fma4(float4& acc, float s, const float4 w) {
    acc.x += s * w.x; acc.y += s * w.y; acc.z += s * w.z; acc.w += s * w.w;
}

// ----------------------------- graph build ---------------------------------

__global__ __launch_bounds__(256) void bucket_count_k(const int* __restrict__ dst,
                                                      int* __restrict__ bucketCount,
                                                      int E, int B) {
    __shared__ int cnt[BMAX];
    for (int i = threadIdx.x; i < B; i += 256) cnt[i] = 0;
    __syncthreads();
    int base = blockIdx.x * CHUNK;
    #pragma unroll
    for (int t = 0; t < EPT; t++) {
        int e = base + t * 256 + threadIdx.x;
        if (e < E) atomicAdd(&cnt[dst[e] >> BSHIFT], 1);
    }
    __syncthreads();
    for (int i = threadIdx.x; i < B; i += 256)
        if (cnt[i] > 0) atomicAdd(&bucketCount[i], cnt[i]);
}

__global__ __launch_bounds__(64) void bucket_scan_k(const int* __restrict__ bucketCount,
                                                    int* __restrict__ bucketPtr,
                                                    int* __restrict__ bucketCursor,
                                                    int* __restrict__ rowPtr,
                                                    int B, int N, int E) {
    int lane = threadIdx.x;
    const int PT = (BMAX + 63) / 64;
    int v[PT]; int s = 0;
    #pragma unroll
    for (int t = 0; t < PT; t++) {
        int i = lane * PT + t;
        v[t] = (i < B) ? bucketCount[i] : 0;
        s += v[t];
    }
    int x = s;
    #pragma unroll
    for (int off = 1; off < 64; off <<= 1) {
        int y = __shfl_up(x, off, 64);
        if (lane >= off) x += y;
    }
    int run = x - s;
    #pragma unroll
    for (int t = 0; t < PT; t++) {
        int i = lane * PT + t;
        if (i < B) { bucketPtr[i] = run; bucketCursor[i] = run; }
        run += v[t];
    }
    if (lane == 63) bucketPtr[B] = x;
    if (lane == 0) rowPtr[N] = E;
}

__global__ __launch_bounds__(256) void bucket_scatter_k(const int* __restrict__ src,
                                                        const int* __restrict__ dst,
                                                        int* __restrict__ bucketCursor,
                                                        int* __restrict__ ebuf,
                                                        int E, int B) {
    __shared__ int cnt[BMAX];
    __shared__ int base[BMAX];
    __shared__ int cur[BMAX];
    for (int i = threadIdx.x; i < B; i += 256) { cnt[i] = 0; cur[i] = 0; }
    __syncthreads();
    int cbase = blockIdx.x * CHUNK;
    int d[EPT];
    #pragma unroll
    for (int t = 0; t < EPT; t++) {
        int e = cbase + t * 256 + threadIdx.x;
        d[t] = (e < E) ? dst[e] : -1;
        if (d[t] >= 0) atomicAdd(&cnt[d[t] >> BSHIFT], 1);
    }
    __syncthreads();
    for (int i = threadIdx.x; i < B; i += 256)
        if (cnt[i] > 0) base[i] = atomicAdd(&bucketCursor[i], cnt[i]);
    __syncthreads();
    #pragma unroll
    for (int t = 0; t < EPT; t++) {
        int e = cbase + t * 256 + threadIdx.x;
        if (d[t] >= 0) {
            int b = d[t] >> BSHIFT;
            int c = atomicAdd(&cur[b], 1);
            int pack = (src[e] & 0xFFFF) | ((d[t] & (BNODES - 1)) << 16);
            ebuf[base[b] + c] = pack;
        }
    }
}

__global__ __launch_bounds__(256) void csr_build_k(const int* __restrict__ ebuf,
                                                   const int* __restrict__ bucketPtr,
                                                   int* __restrict__ rowPtr,
                                                   float* __restrict__ dinv,
                                                   int* __restrict__ srcSorted,
                                                   int N) {
    __shared__ int deg[BNODES];
    __shared__ int rp[BNODES + 1];
    __shared__ int cur[BNODES];
    __shared__ int stage[CAP];
    int b = blockIdx.x;
    int nodeBase = b << BSHIFT;
    int nNodes = min(BNODES, N - nodeBase);
    int eBase = bucketPtr[b];
    int eCnt = bucketPtr[b + 1] - eBase;
    for (int i = threadIdx.x; i < BNODES; i += 256) deg[i] = 0;
    __syncthreads();
    for (int i = threadIdx.x; i < eCnt; i += 256)
        atomicAdd(&deg[(ebuf[eBase + i] >> 16) & (BNODES - 1)], 1);
    __syncthreads();
    if (threadIdx.x < 64) {
        int lane = threadIdx.x;
        int d0 = deg[2 * lane], d1 = deg[2 * lane + 1];
        int s = d0 + d1;
        int x = s;
        #pragma unroll
        for (int off = 1; off < 64; off <<= 1) {
            int y = __shfl_up(x, off, 64);
            if (lane >= off) x += y;
        }
        int ex = x - s;
        rp[2 * lane] = ex;
        rp[2 * lane + 1] = ex + d0;
        cur[2 * lane] = ex;
        cur[2 * lane + 1] = ex + d0;
        if (lane == 63) rp[BNODES] = x;
    }
    __syncthreads();
    for (int j = threadIdx.x; j < nNodes; j += 256) {
        rowPtr[nodeBase + j] = eBase + rp[j];
        int dg = deg[j];
        dinv[nodeBase + j] = rsqrtf((float)(dg > 1 ? dg : 1));
    }
    if (eCnt <= CAP) {
        for (int i = threadIdx.x; i < eCnt; i += 256) {
            int p = ebuf[eBase + i];
            int ld = (p >> 16) & (BNODES - 1);
            int pos = atomicAdd(&cur[ld], 1);
            stage[pos] = p & 0xFFFF;
        }
        __syncthreads();
        for (int i = threadIdx.x; i < eCnt; i += 256)
            srcSorted[eBase + i] = stage[i];
    } else {
        for (int i = threadIdx.x; i < eCnt; i += 256) {
            int p = ebuf[eBase + i];
            int ld = (p >> 16) & (BNODES - 1);
            int pos = atomicAdd(&cur[ld], 1);
            srcSorted[eBase + pos] = p & 0xFFFF;
        }
    }
}

// ----------------------------- dense1 --------------------------------------
// Thread per node, AoS in/out, LDS-bounced contiguous output writes.

#define D1_BLK 128
#define D1_PAD 68

__global__ __launch_bounds__(D1_BLK) void dense1_k(const float* __restrict__ Xg,
                                                   const float* __restrict__ W1,
                                                   const float* __restrict__ b1,
                                                   float* __restrict__ h1, int N) {
    __shared__ float lds[D1_BLK * D1_PAD];
    int n0 = blockIdx.x * D1_BLK;
    int n = n0 + threadIdx.x;
    bool act = (n < N);
    const float4* W = (const float4*)W1;
    const float4* B = (const float4*)b1;
    float4 acc[16];
    #pragma unroll
    for (int j = 0; j < 16; j++) acc[j] = B[j];
    if (act) {
        const float4* X = (const float4*)Xg + (size_t)n * 32;
        float4 a = X[0];
        #pragma unroll 1
        for (int kc = 0; kc < 32; kc++) {
            float4 an = a;
            if (kc + 1 < 32) an = X[kc + 1];
            const float4* wrow = W + kc * 64;
            #pragma unroll
            for (int j = 0; j < 16; j++) {
                fma4(acc[j], a.x, wrow[j]);
                fma4(acc[j], a.y, wrow[16 + j]);
                fma4(acc[j], a.z, wrow[32 + j]);
                fma4(acc[j], a.w, wrow[48 + j]);
            }
            a = an;
        }
    }
    float* myrow = &lds[threadIdx.x * D1_PAD];
    #pragma unroll
    for (int j = 0; j < 16; j++) {
        float4 v = acc[j];
        *(float4*)&myrow[4 * j] = make_float4(fmaxf(v.x, 0.f), fmaxf(v.y, 0.f),
                                              fmaxf(v.z, 0.f), fmaxf(v.w, 0.f));
    }
    __syncthreads();
    float4* o4 = (float4*)h1;
    #pragma unroll
    for (int r = 0; r < 16; r++) {
        int idx = r * D1_BLK + threadIdx.x;
        int row = idx >> 4, col = idx & 15;
        int gn = n0 + row;
        if (gn < N) o4[(size_t)gn * 16 + col] = *(float4*)&lds[row * D1_PAD + col * 4];
    }
}

// ----------------------------- dense2res -----------------------------------
// Thread per node. Outputs h, hs (=h*dinv), res via LDS bounce; th = h.Wattn.

#define D2_BLK 128
#define D2_PAD 68

__global__ __launch_bounds__(D2_BLK) void dense2res_k(const float* __restrict__ h1,
                                                      const float* __restrict__ W2,
                                                      const float* __restrict__ b2,
                                                      const float* __restrict__ Wres,
                                                      const float* __restrict__ bres,
                                                      const float* __restrict__ Wattn,
                                                      const float* __restrict__ dinv,
                                                      float* __restrict__ hg,
                                                      float* __restrict__ hsg,
                                                      float* __restrict__ resg,
                                                      float* __restrict__ thv, int N) {
    __shared__ float lds[D2_BLK * D2_PAD];
    int n0 = blockIdx.x * D2_BLK;
    int n = n0 + threadIdx.x;
    bool act = (n < N);
    const float4* W = (const float4*)W2;
    const float4* B = (const float4*)b2;
    float4 acc[16];
    #pragma unroll
    for (int j = 0; j < 16; j++) acc[j] = B[j];
    if (act) {
        const float4* X = (const float4*)h1 + (size_t)n * 16;
        float4 a = X[0];
        #pragma unroll 1
        for (int kc = 0; kc < 16; kc++) {
            float4 an = a;
            if (kc + 1 < 16) an = X[kc + 1];
            const float4* wrow = W + kc * 64;
            #pragma unroll
            for (int j = 0; j < 16; j++) {
                fma4(acc[j], a.x, wrow[j]);
                fma4(acc[j], a.y, wrow[16 + j]);
                fma4(acc[j], a.z, wrow[32 + j]);
                fma4(acc[j], a.w, wrow[48 + j]);
            }
            a = an;
        }
    }
    // relu; stage h; attention score
    const float4* Wa = (const float4*)Wattn;
    float th = 0.f;
    float* myrow = &lds[threadIdx.x * D2_PAD];
    #pragma unroll
    for (int j = 0; j < 16; j++) {
        float4 v = acc[j];
        v.x = fmaxf(v.x, 0.f); v.y = fmaxf(v.y, 0.f);
        v.z = fmaxf(v.z, 0.f); v.w = fmaxf(v.w, 0.f);
        acc[j] = v;
        *(float4*)&myrow[4 * j] = v;
        float4 w = Wa[j];
        th += v.x * w.x + v.y * w.y + v.z * w.z + v.w * w.w;
    }
    if (act) thv[n] = th;
    __syncthreads();
    // coop contiguous writes of h and hs
    float4* h4 = (float4*)hg;
    float4* hs4 = (float4*)hsg;
    #pragma unroll
    for (int r = 0; r < 16; r++) {
        int idx = r * D2_BLK + threadIdx.x;
        int row = idx >> 4, col = idx & 15;
        int gn = n0 + row;
        if (gn < N) {
            float4 v = *(float4*)&lds[row * D2_PAD + col * 4];
            h4[(size_t)gn * 16 + col] = v;
            float di = dinv[gn];
            hs4[(size_t)gn * 16 + col] = make_float4(v.x * di, v.y * di,
                                                     v.z * di, v.w * di);
        }
    }
    // res = h @ Wres + bres (h still in regs)
    const float4* WR = (const float4*)Wres;
    const float4* BR = (const float4*)bres;
    float4 acc2[16];
    #pragma unroll
    for (int j = 0; j < 16; j++) acc2[j] = BR[j];
    #pragma unroll 1
    for (int kc = 0; kc < 16; kc++) {
        float4 a2 = acc[kc];
        const float4* wrow = WR + kc * 64;
        #pragma unroll
        for (int j = 0; j < 16; j++) {
            fma4(acc2[j], a2.x, wrow[j]);
            fma4(acc2[j], a2.y, wrow[16 + j]);
            fma4(acc2[j], a2.z, wrow[32 + j]);
            fma4(acc2[j], a2.w, wrow[48 + j]);
        }
    }
    __syncthreads();   // h/hs coop reads done before overwrite
    #pragma unroll
    for (int j = 0; j < 16; j++) *(float4*)&myrow[4 * j] = acc2[j];
    __syncthreads();
    float4* r4 = (float4*)resg;
    #pragma unroll
    for (int r = 0; r < 16; r++) {
        int idx = r * D2_BLK + threadIdx.x;
        int row = idx >> 4, col = idx & 15;
        int gn = n0 + row;
        if (gn < N) r4[(size_t)gn * 16 + col] = *(float4*)&lds[row * D2_PAD + col * 4];
    }
}

// ----------------------------- SPMM (spmm1) --------------------------------
// Wave per node (4/block). Outputs u1 AoS, u1s AoS, ta = u1.Wattn.

__global__ __launch_bounds__(256) void spmm_k(const float4* __restrict__ xs,
                                              const int* __restrict__ srcs,
                                              const int* __restrict__ rowPtr,
                                              const float* __restrict__ dinv,
                                              const float* __restrict__ Wattn,
                                              float4* __restrict__ u,
                                              float4* __restrict__ us,
                                              float* __restrict__ tav, int N) {
    int node = (blockIdx.x * 256 + threadIdx.x) >> 6;
    if (node >= N) return;
    int lane = threadIdx.x & 63;
    int sub = lane >> 4;
    int q = lane & 15;
    int s0 = rowPtr[node], s1 = rowPtr[node + 1];
    float4 a0 = make_float4(0.f, 0.f, 0.f, 0.f);
    float4 a1 = make_float4(0.f, 0.f, 0.f, 0.f);
    int i = s0 + sub;
    for (; i + 4 < s1; i += 8) {
        int sA = srcs[i];
        int sB = srcs[i + 4];
        float4 vA = xs[(size_t)sA * 16 + q];
        float4 vB = xs[(size_t)sB * 16 + q];
        a0.x += vA.x; a0.y += vA.y; a0.z += vA.z; a0.w += vA.w;
        a1.x += vB.x; a1.y += vB.y; a1.z += vB.z; a1.w += vB.w;
    }
    if (i < s1) {
        int sA = srcs[i];
        float4 vA = xs[(size_t)sA * 16 + q];
        a0.x += vA.x; a0.y += vA.y; a0.z += vA.z; a0.w += vA.w;
    }
    a0.x += a1.x; a0.y += a1.y; a0.z += a1.z; a0.w += a1.w;
    #pragma unroll
    for (int m = 16; m < 64; m <<= 1) {
        a0.x += __shfl_xor(a0.x, m, 64);
        a0.y += __shfl_xor(a0.y, m, 64);
        a0.z += __shfl_xor(a0.z, m, 64);
        a0.w += __shfl_xor(a0.w, m, 64);
    }
    if (sub == 0) {
        float di = dinv[node];
        float4 r = make_float4(a0.x * di, a0.y * di, a0.z * di, a0.w * di);
        u[(size_t)node * 16 + q] = r;
        us[(size_t)node * 16 + q] = make_float4(r.x * di, r.y * di,
                                                r.z * di, r.w * di);
        float4 w = ((const float4*)Wattn)[q];
        float p = r.x * w.x + r.y * w.y + r.z * w.z + r.w * w.w;
        #pragma unroll
        for (int m = 1; m < 16; m <<= 1) p += __shfl_xor(p, m, 64);
        if (lane == 0) tav[node] = p;
    }
}

// ----------------------------- fused spmm2 + tail --------------------------
// Wave per node (4/block). u2 lives only in registers/LDS. After gather:
// lane j owns feature j; wave-GEMVs via shfl broadcast of the input vector.

#define TL_PAD 68

__global__ __launch_bounds__(256) void tail_k(const float4* __restrict__ u1s,
                                              const int* __restrict__ srcs,
                                              const int* __restrict__ rowPtr,
                                              const float* __restrict__ dinv,
                                              const float* __restrict__ hg,
                                              const float* __restrict__ u1g,
                                              const float* __restrict__ resg,
                                              const float* __restrict__ thv,
                                              const float* __restrict__ tav,
                                              const float* __restrict__ Wattn,
                                              const float* __restrict__ battn,
                                              const float* __restrict__ Wf1,
                                              const float* __restrict__ bf1,
                                              const float* __restrict__ Wf2,
                                              const float* __restrict__ bf2,
                                              const float* __restrict__ W3,
                                              const float* __restrict__ b3,
                                              const float* __restrict__ W4,
                                              const float* __restrict__ b4,
                                              float2* __restrict__ out, int N) {
    __shared__ float lds[4 * TL_PAD];
    int w = threadIdx.x >> 6;
    int lane = threadIdx.x & 63;
    int node = blockIdx.x * 4 + w;
    bool active = (node < N);
    int sub = lane >> 4, q = lane & 15;
    if (active) {
        int s0 = rowPtr[node], s1 = rowPtr[node + 1];
        float4 a0 = make_float4(0.f, 0.f, 0.f, 0.f);
        float4 a1 = make_float4(0.f, 0.f, 0.f, 0.f);
        int i = s0 + sub;
        for (; i + 4 < s1; i += 8) {
            int sA = srcs[i];
            int sB = srcs[i + 4];
            float4 vA = u1s[(size_t)sA * 16 + q];
            float4 vB = u1s[(size_t)sB * 16 + q];
            a0.x += vA.x; a0.y += vA.y; a0.z += vA.z; a0.w += vA.w;
            a1.x += vB.x; a1.y += vB.y; a1.z += vB.z; a1.w += vB.w;
        }
        if (i < s1) {
            int sA = srcs[i];
            float4 vA = u1s[(size_t)sA * 16 + q];
            a0.x += vA.x; a0.y += vA.y; a0.z += vA.z; a0.w += vA.w;
        }
        a0.x += a1.x; a0.y += a1.y; a0.z += a1.z; a0.w += a1.w;
        #pragma unroll
        for (int m = 16; m < 64; m <<= 1) {
            a0.x += __shfl_xor(a0.x, m, 64);
            a0.y += __shfl_xor(a0.y, m, 64);
            a0.z += __shfl_xor(a0.z, m, 64);
            a0.w += __shfl_xor(a0.w, m, 64);
        }
        if (sub == 0) {
            float di = dinv[node];
            *(float4*)&lds[w * TL_PAD + q * 4] =
                make_float4(a0.x * di, a0.y * di, a0.z * di, a0.w * di);
        }
    }
    __syncthreads();
    if (!active) return;
    float u2j = lds[w * TL_PAD + lane];                  // feature j = lane
    float hj = hg[(size_t)node * 64 + lane];
    float u1j = u1g[(size_t)node * 64 + lane];
    float resj = resg[(size_t)node * 64 + lane];
    // tb = u2 . Wattn
    float tb = u2j * Wattn[lane];
    #pragma unroll
    for (int m = 1; m < 64; m <<= 1) tb += __shfl_xor(tb, m, 64);
    float th = thv[node], ta = tav[node], ba = battn[0];
    float s0 = 0.75f * th + 1.5f * ta + 0.75f * tb + ba;
    float s1 = 1.5f * th - 1.5f * tb + ba;
    float s2 = 0.75f * th - 1.5f * ta + 0.75f * tb + ba;
    float mx = fmaxf(s0, fmaxf(s1, s2));
    float e0 = expf(s0 - mx), e1 = expf(s1 - mx), e2 = expf(s2 - mx);
    float inv = 1.f / (e0 + e1 + e2);
    float w0 = e0 * inv, w1 = e1 * inv, w2 = e2 * inv;
    float ca = 0.75f * w0 + 1.5f * w1 + 0.75f * w2;
    float cb = 1.5f * (w0 - w2);
    float cc = 0.75f * w0 - 1.5f * w1 + 0.75f * w2;
    float afj = ca * hj + cb * u1j + cc * u2j;
    // t = relu([af | h] @ Wf1 + bf1)  (wave-GEMV, shfl-broadcast inputs)
    float t = bf1[lane];
    #pragma unroll 4
    for (int k = 0; k < 64; k++) {
        float afk = __shfl(afj, k, 64);
        float hk = __shfl(hj, k, 64);
        t += afk * Wf1[k * 64 + lane] + hk * Wf1[(64 + k) * 64 + lane];
    }
    t = fmaxf(t, 0.f);
    float fwacc = t * Wf2[lane];
    #pragma unroll
    for (int m = 1; m < 64; m <<= 1) fwacc += __shfl_xor(fwacc, m, 64);
    float fw = 1.f / (1.f + expf(-(fwacc + bf2[0])));
    // fused = 0.1*fw*af + (1-fw)*h + 0.8*res   (mean_fused == h exactly)
    float fj = 0.1f * fw * afj + (1.f - fw) * hj + 0.8f * resj;
    float g = b3[lane];
    #pragma unroll 4
    for (int k = 0; k < 64; k++) {
        float fk = __shfl(fj, k, 64);
        g += fk * W3[k * 64 + lane];
    }
    g = fmaxf(g, 0.f);
    float2 w4 = ((const float2*)W4)[lane];
    float l0 = g * w4.x, l1 = g * w4.y;
    #pragma unroll
    for (int m = 1; m < 64; m <<= 1) {
        l0 += __shfl_xor(l0, m, 64);
        l1 += __shfl_xor(l1, m, 64);
    }
    if (lane == 0) out[node] = make_float2(l0 + b4[0], l1 + b4[1]);
}

// ----------------------------- launch --------------------------------------

extern "C" void kernel_launch(void* const* d_in, const int* in_sizes, int n_in,
                              void* d_out, int out_size, void* d_ws, size_t ws_size,
                              hipStream_t stream) {
    const float* in_feat = (const float*)d_in[0];
    const int*   src     = (const int*)d_in[1];
    const int*   dst     = (const int*)d_in[2];
    const float* W1   = (const float*)d_in[3];
    const float* b1   = (const float*)d_in[4];
    const float* W2   = (const float*)d_in[5];
    const float* b2   = (const float*)d_in[6];
    const float* Wres = (const float*)d_in[7];
    const float* bres = (const float*)d_in[8];
    const float* Wattn = (const float*)d_in[9];
    const float* battn = (const float*)d_in[10];
    const float* Wf1  = (const float*)d_in[11];
    const float* bf1  = (const float*)d_in[12];
    const float* Wf2  = (const float*)d_in[13];
    const float* bf2  = (const float*)d_in[14];
    const float* W3   = (const float*)d_in[15];
    const float* b3   = (const float*)d_in[16];
    const float* W4   = (const float*)d_in[17];
    const float* b4   = (const float*)d_in[18];

    const int N = in_sizes[0] / 128;
    const int E = in_sizes[1];
    const int B = (N + BNODES - 1) >> BSHIFT;

    char* p = (char*)d_ws;
    auto take = [&](size_t bytes) -> char* {
        char* r = p;
        p += (bytes + 255) & ~(size_t)255;
        return r;
    };
    int*   bucketCount  = (int*)take((size_t)(B + 1) * 4);
    int*   bucketPtr    = (int*)take((size_t)(B + 1) * 4);
    int*   bucketCursor = (int*)take((size_t)(B + 1) * 4);
    int*   rowPtr       = (int*)take((size_t)(N + 1) * 4);
    float* dinv         = (float*)take((size_t)N * 4);
    int*   srcSorted    = (int*)take((size_t)E * 4);
    float* thv          = (float*)take((size_t)N * 4);
    float* tav          = (float*)take((size_t)N * 4);
    float* h1  = (float*)take((size_t)N * 256);
    float* h   = (float*)take((size_t)N * 256);
    float* hs  = (float*)take((size_t)N * 256);
    float* res = (float*)take((size_t)N * 256);
    float* u1  = (float*)take((size_t)N * 256);
    float* u1s = (float*)take((size_t)N * 256);
    int*   ebuf = (int*)h1;   // dead before dense1 writes h1 (stream order)

    int eb = (E + CHUNK - 1) / CHUNK;
    int d1b = (N + D1_BLK - 1) / D1_BLK;
    int d2b = (N + D2_BLK - 1) / D2_BLK;
    int spb = (N * 64 + 255) / 256;
    int tlb = (N + 3) / 4;

    hipMemsetAsync(bucketCount, 0, (size_t)B * 4, stream);
    bucket_count_k<<<eb, 256, 0, stream>>>(dst, bucketCount, E, B);
    bucket_scan_k<<<1, 64, 0, stream>>>(bucketCount, bucketPtr, bucketCursor,
                                        rowPtr, B, N, E);
    bucket_scatter_k<<<eb, 256, 0, stream>>>(src, dst, bucketCursor, ebuf, E, B);
    csr_build_k<<<B, 256, 0, stream>>>(ebuf, bucketPtr, rowPtr, dinv, srcSorted, N);

    dense1_k<<<d1b, D1_BLK, 0, stream>>>(in_feat, W1, b1, h1, N);
    dense2res_k<<<d2b, D2_BLK, 0, stream>>>(h1, W2, b2, Wres, bres, Wattn, dinv,
                                            h, hs, res, thv, N);

    spmm_k<<<spb, 256, 0, stream>>>((const float4*)hs, srcSorted, rowPtr, dinv,
                                    Wattn, (float4*)u1, (float4*)u1s, tav, N);

    tail_k<<<tlb, 256, 0, stream>>>((const float4*)u1s, srcSorted, rowPtr, dinv,
                                    h, u1, res, thv, tav, Wattn, battn,
                                    Wf1, bf1, Wf2, bf2, W3, b3, W4, b4,
                                    (float2*)d_out, N);
}